// Round 14
// baseline (225.399 us; speedup 1.0000x reference)
//
#include <hip/hip_runtime.h>
#include <cstdint>
#include <cstddef>

#define BB 4
#define SS 2048
#define DD 1024
#define HH 16

typedef __bf16 bf16;
typedef __bf16 bf16x8 __attribute__((ext_vector_type(8)));
typedef __bf16 bf16x4 __attribute__((ext_vector_type(4)));
typedef float f32x4 __attribute__((ext_vector_type(4)));
typedef unsigned int u32;

typedef __attribute__((address_space(1))) const void* as1_cvoid;
typedef __attribute__((address_space(3))) void* as3_void;

__device__ __forceinline__ void gload_lds16(const void* g, void* l) {
  __builtin_amdgcn_global_load_lds((as1_cvoid)g, (as3_void)l, 16, 0, 0);
}

// ---------------- K0: per-batch masked count ----------------
__global__ void mask_count_kernel(const unsigned char* __restrict__ mask, int* __restrict__ nm) {
  int wid = threadIdx.x >> 6, lane = threadIdx.x & 63;
  if (wid >= BB) return;
  int s = 0;
  for (int i = lane; i < SS; i += 64) s += (mask[wid * SS + i] != 0) ? 1 : 0;
#pragma unroll
  for (int m = 1; m < 64; m <<= 1) s += __shfl_xor(s, m);
  if (lane == 0) nm[wid] = s;
}

// ---------------- K1a: all 4 weight matrices in one launch ----------------
__global__ void cvt4_kernel(const float* __restrict__ W0, const float* __restrict__ W1,
                            const float* __restrict__ W2, const float* __restrict__ W3,
                            bf16* __restrict__ D0, bf16* __restrict__ D1,
                            bf16* __restrict__ D2, bf16* __restrict__ D3) {
  int which = blockIdx.x >> 8;  // 4 x 256 blocks
  const float* src = which == 0 ? W0 : which == 1 ? W1 : which == 2 ? W2 : W3;
  bf16* dst = which == 0 ? D0 : which == 1 ? D1 : which == 2 ? D2 : D3;
  const int n4 = DD * DD / 4;
  for (int i = (blockIdx.x & 255) * 256 + threadIdx.x; i < n4; i += 65536) {
    float4 v = ((const float4*)src)[i];
    bf16x4 o;
    o[0] = (bf16)v.x; o[1] = (bf16)v.y; o[2] = (bf16)v.z; o[3] = (bf16)v.w;
    ((bf16x4*)dst)[i] = o;
  }
}

// ---------------- K1b: RoPE sin/cos table ----------------
__global__ void sincos_table_kernel(const int* __restrict__ nm, float2* __restrict__ tbl) {
  int g = blockIdx.x * 256 + threadIdx.x;  // (b*S+s)*32 + j
  int j = g & 31;
  int idx = g >> 5;
  int b = idx >> 11, s = idx & 2047;
  int pos = s - nm[b];
  float inv_ts = __expf((float)j * (-9.210340371976184f / 32.0f));
  float sn, cs;
  sincosf((float)pos * inv_ts, &sn, &cs);
  tbl[g] = make_float2(cs, sn);
}

// ---------------- K2: QKV GEMM (R12 2-phase 128x128) + fused f32 A-convert ----------------
// A staged from f32 X via reg-staging (float4 load -> cvt -> ds_write_b64): the
// separate 48MB cvt pass is deleted. B (weights, bf16) stays global_load_lds.
// B gloads issue first so they fly during the A convert. Epilogue as R12.
__global__ void __launch_bounds__(256) gemm_qkv_kernel(
    const float* __restrict__ X, const bf16* __restrict__ Wq, const bf16* __restrict__ Wk,
    const bf16* __restrict__ Wv, const float* __restrict__ qls, const float* __restrict__ kls,
    const float* __restrict__ pds, const float2* __restrict__ tbl,
    bf16* __restrict__ Qp, bf16* __restrict__ Kp, bf16* __restrict__ Vt) {
  __shared__ __align__(16) char smem[4 * 64 * 72 * 2];
  bf16* Ab = (bf16*)smem;
  bf16* Bb = (bf16*)(smem + 8192);
  const int tid = threadIdx.x;
  const int wid = tid >> 6, lane = tid & 63;
  const int lr = lane & 15, lg = lane >> 4;
  const int nx = 24;
  const int cpx = gridDim.x >> 3;
  const int lid = (blockIdx.x & 7) * cpx + (blockIdx.x >> 3);
  const int m0 = (lid / nx) * 128;
  const int ntile = lid % nx;
  const int which = ntile >> 3;
  const int n0 = (ntile & 7) * 128;
  const bf16* Bm = which == 0 ? Wq : (which == 1 ? Wk : Wv);
  const int wm = (wid >> 1) * 64, wn = (wid & 1) * 64;

  // hoisted A-staging addresses: per qi, idx = qi*256+tid; row=idx>>3, chunk=idx&7
  // (8 lanes cover one row's 128B contiguous f32 -> coalesced)
  const float* ag[4];
  char* al[4];
#pragma unroll
  for (int qi = 0; qi < 4; ++qi) {
    int idx = qi * 256 + tid;
    int row = idx >> 3, chunk = idx & 7;
    ag[qi] = X + (size_t)(m0 + row) * DD + chunk * 4;
    al[qi] = (char*)Ab + row * 64 + chunk * 8;
  }

  f32x4 acc[4][4] = {};
  for (int k0 = 0; k0 < DD; k0 += 32) {
    __syncthreads();
    // B first (async gload flies during A convert)
#pragma unroll
    for (int i = 0; i < 2; ++i) {
      int o = i * 4096 + tid * 16;
      int row = o >> 6;
      int ke = (o & 63) >> 1;
      gload_lds16(Bm + (size_t)(n0 + row) * DD + k0 + ke, (char*)Bb + o);
    }
    // A: f32 load -> bf16 cvt -> LDS
    float4 va0 = *(const float4*)(ag[0] + k0);
    float4 va1 = *(const float4*)(ag[1] + k0);
    float4 va2 = *(const float4*)(ag[2] + k0);
    float4 va3 = *(const float4*)(ag[3] + k0);
    {
      union { bf16 h[4]; uint2 u; } w0, w1, w2, w3;
      w0.h[0] = (bf16)va0.x; w0.h[1] = (bf16)va0.y; w0.h[2] = (bf16)va0.z; w0.h[3] = (bf16)va0.w;
      w1.h[0] = (bf16)va1.x; w1.h[1] = (bf16)va1.y; w1.h[2] = (bf16)va1.z; w1.h[3] = (bf16)va1.w;
      w2.h[0] = (bf16)va2.x; w2.h[1] = (bf16)va2.y; w2.h[2] = (bf16)va2.z; w2.h[3] = (bf16)va2.w;
      w3.h[0] = (bf16)va3.x; w3.h[1] = (bf16)va3.y; w3.h[2] = (bf16)va3.z; w3.h[3] = (bf16)va3.w;
      *(uint2*)al[0] = w0.u;
      *(uint2*)al[1] = w1.u;
      *(uint2*)al[2] = w2.u;
      *(uint2*)al[3] = w3.u;
    }
    __syncthreads();
    bf16x8 af[4], bf_[4];
#pragma unroll
    for (int i = 0; i < 4; ++i) af[i] = *(const bf16x8*)&Ab[(wm + i * 16 + lr) * 32 + lg * 8];
#pragma unroll
    for (int j = 0; j < 4; ++j) bf_[j] = *(const bf16x8*)&Bb[(wn + j * 16 + lr) * 32 + lg * 8];
#pragma unroll
    for (int i = 0; i < 4; ++i)
#pragma unroll
      for (int j = 0; j < 4; ++j)
        acc[i][j] = __builtin_amdgcn_mfma_f32_16x16x32_bf16(af[i], bf_[j], acc[i][j], 0, 0, 0);
  }
  const int b = m0 >> 11;
  const int s0g = m0 & 2047;
  const int hq = n0 >> 6;
  if (which < 2) {
    float scj[4];
#pragma unroll
    for (int j = 0; j < 4; ++j) {
      int d = j * 16 + lr;
      scj[j] = (which == 0) ? qls[d] * 0.26017112262570096f * log1pf(__expf(pds[d]))
                            : kls[d];
    }
    bf16* Out = which == 0 ? Qp : Kp;
    const int h = hq + (wn >> 6);
    const size_t base = (size_t)(b * 16 + h) * SS;
#pragma unroll
    for (int i = 0; i < 4; ++i)
#pragma unroll
      for (int r = 0; r < 4; ++r) {
        int srow = s0g + wm + i * 16 + lg * 4 + r;
        const float2* trow = tbl + ((size_t)(b * SS + srow) << 5);
        float2 t0 = trow[lr], t1 = trow[16 + lr];
        float a0 = acc[i][0][r], a1 = acc[i][1][r], a2 = acc[i][2][r], a3 = acc[i][3][r];
        float n0_ = a0 * t0.x - a2 * t0.y;
        float n2_ = a2 * t0.x + a0 * t0.y;
        float n1_ = a1 * t1.x - a3 * t1.y;
        float n3_ = a3 * t1.x + a1 * t1.y;
        float ssum = n0_ * n0_ + n1_ * n1_ + n2_ * n2_ + n3_ * n3_;
        ssum += __shfl_xor(ssum, 1);
        ssum += __shfl_xor(ssum, 2);
        ssum += __shfl_xor(ssum, 4);
        ssum += __shfl_xor(ssum, 8);
        float rinv = rsqrtf(ssum * (1.0f / 64.0f) + 1e-6f);
        bf16* orow = Out + (base + srow) * 64;
        orow[lr]      = (bf16)(n0_ * rinv * scj[0]);
        orow[16 + lr] = (bf16)(n1_ * rinv * scj[1]);
        orow[32 + lr] = (bf16)(n2_ * rinv * scj[2]);
        orow[48 + lr] = (bf16)(n3_ * rinv * scj[3]);
      }
  } else {
    __syncthreads();
    bf16* tw = (bf16*)smem + wid * 64 * 72;
#pragma unroll
    for (int i = 0; i < 4; ++i)
#pragma unroll
      for (int j = 0; j < 4; ++j)
#pragma unroll
        for (int r = 0; r < 4; ++r)
          tw[(j * 16 + lr) * 72 + i * 16 + lg * 4 + r] = (bf16)acc[i][j][r];
    __syncthreads();
    int d = tid >> 2, sc = (tid & 3) * 16;
#pragma unroll
    for (int w = 0; w < 4; ++w) {
      int rh = w >> 1, hh = w & 1;
      const bf16* ts = (const bf16*)smem + w * 64 * 72 + d * 72 + sc;
      bf16x8 v0 = *(const bf16x8*)ts;
      bf16x8 v1 = *(const bf16x8*)(ts + 8);
      size_t vo = ((size_t)((b * 16 + hq + hh) * 64 + d)) * SS + s0g + rh * 64 + sc;
      *(bf16x8*)(Vt + vo) = v0;
      *(bf16x8*)(Vt + vo + 8) = v1;
    }
  }
}

// ---------------- K5: C[M,N] = A[M,K] @ B[N,K]^T (f32 out, for Wo) ----------------
__global__ void __launch_bounds__(256) gemm_bt_kernel(const bf16* __restrict__ A,
                                                      const bf16* __restrict__ Bm,
                                                      float* __restrict__ Cout,
                                                      int M, int N, int K) {
  __shared__ bf16 Ab[128 * 32];
  __shared__ bf16 Bb[128 * 32];
  const int tid = threadIdx.x;
  const int wid = tid >> 6, lane = tid & 63;
  const int lr = lane & 15, lg = lane >> 4;
  const int nx = N >> 7;
  const int cpx = gridDim.x >> 3;
  const int lid = (blockIdx.x & 7) * cpx + (blockIdx.x >> 3);
  const int m0 = (lid / nx) * 128, n0 = (lid % nx) * 128;
  const int wm = (wid >> 1) * 64, wn = (wid & 1) * 64;
  f32x4 acc[4][4] = {};
  for (int k0 = 0; k0 < K; k0 += 32) {
    __syncthreads();
#pragma unroll
    for (int i = 0; i < 2; ++i) {
      int o = (wid * 2 + i) * 1024 + lane * 16;
      int row = o >> 6;
      int ke = (o & 63) >> 1;
      gload_lds16(A + (size_t)(m0 + row) * K + k0 + ke, (char*)Ab + o);
      gload_lds16(Bm + (size_t)(n0 + row) * K + k0 + ke, (char*)Bb + o);
    }
    __syncthreads();
    bf16x8 af[4], bf_[4];
#pragma unroll
    for (int i = 0; i < 4; ++i) af[i] = *(const bf16x8*)&Ab[(wm + i * 16 + lr) * 32 + lg * 8];
#pragma unroll
    for (int j = 0; j < 4; ++j) bf_[j] = *(const bf16x8*)&Bb[(wn + j * 16 + lr) * 32 + lg * 8];
#pragma unroll
    for (int i = 0; i < 4; ++i)
#pragma unroll
      for (int j = 0; j < 4; ++j)
        acc[i][j] = __builtin_amdgcn_mfma_f32_16x16x32_bf16(af[i], bf_[j], acc[i][j], 0, 0, 0);
  }
#pragma unroll
  for (int i = 0; i < 4; ++i)
#pragma unroll
    for (int j = 0; j < 4; ++j)
#pragma unroll
      for (int r = 0; r < 4; ++r) {
        int row = m0 + wm + i * 16 + lg * 4 + r;
        int col = n0 + wn + j * 16 + lr;
        Cout[(size_t)row * N + col] = acc[i][j][r];
      }
}

// ---------------- K4: causal flash attention (R12 best: 86.5us, unchanged) ----------------
__global__ void __launch_bounds__(256, 2) flash_kernel(
    const bf16* __restrict__ Qp, const bf16* __restrict__ Kp, const bf16* __restrict__ Vt,
    bf16* __restrict__ O, const int* __restrict__ nm) {
  __shared__ bf16 Kb[2][64 * 64];
  __shared__ bf16 Vb[64 * 64];
  __shared__ u32 Pl[4][16][32];
  const int bh = blockIdx.x & 63;
  const int px = blockIdx.x >> 6;  // 0..15
  const int xA = 31 - px, xB = px;
  const int b = bh >> 4, h = bh & 15;
  const int tid = threadIdx.x;
  const int wid = tid >> 6, lane = tid & 63;
  const int lr = lane & 15, lg = lane >> 4;
  const int sw = (lr & 7) << 2;
  const int nmb = nm[b];
  const int wqA = xA * 64 + wid * 16;
  const int wqB = xB * 64 + wid * 16;
  const int nt = xA + 1;

  const int koffA = lr * 128 + ((lg ^ (lr & 7)) << 4);
  const int koffB = lr * 128 + (((4 + lg) ^ (lr & 7)) << 4);
  const int o0 = tid * 16, o1 = 4096 + tid * 16;
  const int r0 = o0 >> 7, r1 = o1 >> 7;
  const int c0 = ((o0 >> 4) & 7) ^ (r0 & 7), c1 = ((o1 >> 4) & 7) ^ (r1 & 7);
  const bf16* kg0 = Kp + (size_t)bh * (SS * 64) + r0 * 64 + c0 * 8;
  const bf16* kg1 = Kp + (size_t)bh * (SS * 64) + r1 * 64 + c1 * 8;
  const bf16* vg0 = Vt + (size_t)bh * (SS * 64) + (size_t)r0 * SS + c0 * 8;
  const bf16* vg1 = Vt + (size_t)bh * (SS * 64) + (size_t)r1 * SS + c1 * 8;
  char* kl0 = (char*)&Kb[0][0] + o0;
  char* kl1 = (char*)&Kb[0][0] + o1;
  char* vl0 = (char*)Vb + o0;
  char* vl1 = (char*)Vb + o1;
  u32* plw = &Pl[wid][lr][0];

  bf16x8 qfA[2], qfB[2];
#pragma unroll
  for (int kh = 0; kh < 2; ++kh) {
    qfA[kh] = *(const bf16x8*)(Qp + ((size_t)bh * SS + wqA + lr) * 64 + kh * 32 + lg * 8);
    qfB[kh] = *(const bf16x8*)(Qp + ((size_t)bh * SS + wqB + lr) * 64 + kh * 32 + lg * 8);
  }

  float mA = -1e30f, lA = 0.f, mB = -1e30f, lB = 0.f;
  f32x4 oA[4] = {}, oB[4] = {};

  auto STAGE_K = [&](int bi, int t) {
    gload_lds16(kg0 + (size_t)t * 4096, kl0 + bi * 8192);
    gload_lds16(kg1 + (size_t)t * 4096, kl1 + bi * 8192);
  };
  auto STAGE_V = [&](int t) {
    gload_lds16(vg0 + t * 64, vl0);
    gload_lds16(vg1 + t * 64, vl1);
  };

  STAGE_K(0, 0);
  STAGE_V(0);
  __syncthreads();
  int buf = 0;
  for (int t = 0; t < nt; ++t) {
    const int kv0 = t * 64;
    if (t + 1 < nt) STAGE_K(buf ^ 1, t + 1);
    const bool actB = (t <= xB);
    f32x4 sA[4], sB[4];

    const char* kbb = (const char*)&Kb[0][0] + buf * 8192;
    __builtin_amdgcn_s_setprio(1);
#pragma unroll
    for (int j = 0; j < 4; ++j) {
      bf16x8 kf0 = *(const bf16x8*)(kbb + koffA + j * 2048);
      bf16x8 kf1 = *(const bf16x8*)(kbb + koffB + j * 2048);
      f32x4 z = {};
      z = __builtin_amdgcn_mfma_f32_16x16x32_bf16(kf0, qfA[0], z, 0, 0, 0);
      z = __builtin_amdgcn_mfma_f32_16x16x32_bf16(kf1, qfA[1], z, 0, 0, 0);
      sA[j] = z;
      if (actB) {
        f32x4 z2 = {};
        z2 = __builtin_amdgcn_mfma_f32_16x16x32_bf16(kf0, qfB[0], z2, 0, 0, 0);
        z2 = __builtin_amdgcn_mfma_f32_16x16x32_bf16(kf1, qfB[1], z2, 0, 0, 0);
        sB[j] = z2;
      }
    }
    __builtin_amdgcn_s_setprio(0);

    auto SOFTMAX = [&](f32x4* s, float& m_r, float& l_pp, f32x4* oacc, bf16x8* pb,
                       int xS, int wqS) {
      if (t == xS) {
        int qr = wqS + lr;
#pragma unroll
        for (int j = 0; j < 4; ++j) {
          int kvb = kv0 + j * 16 + lg * 4;
#pragma unroll
          for (int r = 0; r < 4; ++r)
            if (kvb + r > qr) s[j][r] = -1e30f;
        }
      }
      if (kv0 < nmb) {
#pragma unroll
        for (int j = 0; j < 4; ++j) {
          int kvb = kv0 + j * 16 + lg * 4;
#pragma unroll
          for (int r = 0; r < 4; ++r)
            if (kvb + r < nmb) s[j][r] = -1e30f;
        }
      }
      float t0 = fmaxf(fmaxf(s[0][0], s[0][1]), s[0][2]);
      float t1 = fmaxf(fmaxf(s[0][3], s[1][0]), s[1][1]);
      float t2 = fmaxf(fmaxf(s[1][2], s[1][3]), s[2][0]);
      float t3 = fmaxf(fmaxf(s[2][1], s[2][2]), s[2][3]);
      float t4 = fmaxf(fmaxf(s[3][0], s[3][1]), s[3][2]);
      float t5 = fmaxf(fmaxf(t0, t1), s[3][3]);
      float pm = fmaxf(fmaxf(t2, t3), fmaxf(t4, t5));
      if (!__all(pm - m_r <= 8.f)) {
        pm = fmaxf(pm, __shfl_xor(pm, 16));
        pm = fmaxf(pm, __shfl_xor(pm, 32));
        float mn = fmaxf(m_r, pm);
        float scl = exp2f(m_r - mn);
        m_r = mn;
        l_pp *= scl;
        f32x4 sv = {scl, scl, scl, scl};
#pragma unroll
        for (int jd = 0; jd < 4; ++jd) oacc[jd] *= sv;
      }
      const float mloc = m_r;
      float lp = l_pp;
#pragma unroll
      for (int j = 0; j < 4; ++j) {
        float p0 = exp2f(s[j][0] - mloc), p1 = exp2f(s[j][1] - mloc);
        float p2 = exp2f(s[j][2] - mloc), p3 = exp2f(s[j][3] - mloc);
        lp += (p0 + p1) + (p2 + p3);
        union { bf16 hx[4]; uint2 u2; } pk;
        pk.hx[0] = (bf16)p0; pk.hx[1] = (bf16)p1;
        pk.hx[2] = (bf16)p2; pk.hx[3] = (bf16)p3;
        *(uint2*)&plw[(j * 8 + lg * 2) ^ sw] = pk.u2;
      }
      l_pp = lp;
#pragma unroll
      for (int kh = 0; kh < 2; ++kh)
        pb[kh] = *(const bf16x8*)&plw[(kh * 16 + lg * 4) ^ sw];
    };

    bf16x8 pbA[2], pbB[2];
    SOFTMAX(sA, mA, lA, oA, pbA, xA, wqA);
    if (actB) SOFTMAX(sB, mB, lB, oB, pbB, xB, wqB);

    if (t > 0) {
      if (t + 1 < nt)
        asm volatile("s_waitcnt vmcnt(2)" ::: "memory");
      else
        asm volatile("s_waitcnt vmcnt(0)" ::: "memory");
      __builtin_amdgcn_s_barrier();
      __builtin_amdgcn_sched_barrier(0);
    }
    __builtin_amdgcn_s_setprio(1);
#pragma unroll
    for (int jd = 0; jd < 4; ++jd) {
      bf16x8 va0 = *(const bf16x8*)((const char*)Vb + koffA + jd * 2048);
      bf16x8 va1 = *(const bf16x8*)((const char*)Vb + koffB + jd * 2048);
      oA[jd] = __builtin_amdgcn_mfma_f32_16x16x32_bf16(va0, pbA[0], oA[jd], 0, 0, 0);
      oA[jd] = __builtin_amdgcn_mfma_f32_16x16x32_bf16(va1, pbA[1], oA[jd], 0, 0, 0);
      if (actB) {
        oB[jd] = __builtin_amdgcn_mfma_f32_16x16x32_bf16(va0, pbB[0], oB[jd], 0, 0, 0);
        oB[jd] = __builtin_amdgcn_mfma_f32_16x16x32_bf16(va1, pbB[1], oB[jd], 0, 0, 0);
      }
    }
    __builtin_amdgcn_s_setprio(0);
    __syncthreads();
    if (t + 1 < nt) STAGE_V(t + 1);
    buf ^= 1;
  }
#pragma unroll
  for (int st = 0; st < 2; ++st) {
    float l = st == 0 ? lA : lB;
    const f32x4* oacc = st == 0 ? oA : oB;
    int wq = st == 0 ? wqA : wqB;
    l += __shfl_xor(l, 16);
    l += __shfl_xor(l, 32);
    float invl = 1.0f / l;
    size_t rowoff = ((size_t)b * SS + wq + lr) * DD + h * 64;
#pragma unroll
    for (int jd = 0; jd < 4; ++jd) {
      f32x4 ov = oacc[jd] * invl;
      bf16x4 hv;
      hv[0] = (bf16)ov[0]; hv[1] = (bf16)ov[1]; hv[2] = (bf16)ov[2]; hv[3] = (bf16)ov[3];
      *(bf16x4*)(O + rowoff + jd * 16 + lg * 4) = hv;
    }
  }
}

// ---------------- host launch ----------------
extern "C" void kernel_launch(void* const* d_in, const int* in_sizes, int n_in,
                              void* d_out, int out_size, void* d_ws, size_t ws_size,
                              hipStream_t stream) {
  const float* X = (const float*)d_in[0];
  const float* Wq = (const float*)d_in[1];
  const float* Wk = (const float*)d_in[2];
  const float* Wv = (const float*)d_in[3];
  const float* Wo = (const float*)d_in[4];
  const float* qls = (const float*)d_in[5];
  const float* kls = (const float*)d_in[6];
  const float* pds = (const float*)d_in[7];
  const unsigned char* mask = (const unsigned char*)d_in[8];

  char* ws = (char*)d_ws;
  size_t off = 0;
  auto alloc = [&](size_t bytes) {
    char* p = ws + off;
    off += (bytes + 255) & ~(size_t)255;
    return p;
  };
  const size_t NTOK = (size_t)BB * SS;  // 8192
  int* nm = (int*)alloc(16);
  bf16* Wqb = (bf16*)alloc((size_t)DD * DD * 2);
  bf16* Wkb = (bf16*)alloc((size_t)DD * DD * 2);
  bf16* Wvb = (bf16*)alloc((size_t)DD * DD * 2);
  bf16* Wob = (bf16*)alloc((size_t)DD * DD * 2);
  bf16* Qp = (bf16*)alloc(NTOK * DD * 2);
  bf16* Kp = (bf16*)alloc(NTOK * DD * 2);
  bf16* Vt = (bf16*)alloc(NTOK * DD * 2);
  bf16* Oat = (bf16*)alloc(NTOK * DD * 2);
  float2* tbl = (float2*)alloc(NTOK * 32 * sizeof(float2));

  mask_count_kernel<<<1, 256, 0, stream>>>(mask, nm);
  cvt4_kernel<<<1024, 256, 0, stream>>>(Wq, Wk, Wv, Wo, Wqb, Wkb, Wvb, Wob);
  sincos_table_kernel<<<1024, 256, 0, stream>>>(nm, tbl);

  gemm_qkv_kernel<<<(int)(NTOK / 128) * 24, 256, 0, stream>>>(X, Wqb, Wkb, Wvb, qls, kls, pds,
                                                              tbl, Qp, Kp, Vt);
  flash_kernel<<<1024, 256, 0, stream>>>(Qp, Kp, Vt, Oat, nm);
  gemm_bt_kernel<<<(int)(NTOK / 128) * (DD / 128), 256, 0, stream>>>(Oat, Wob, (float*)d_out,
                                                                     (int)NTOK, DD, DD);
}

// Round 15
// 201.022 us; speedup vs baseline: 1.1213x; 1.1213x over previous
//
#include <hip/hip_runtime.h>
#include <cstdint>
#include <cstddef>

#define BB 4
#define SS 2048
#define DD 1024
#define HH 16

typedef __bf16 bf16;
typedef __bf16 bf16x8 __attribute__((ext_vector_type(8)));
typedef __bf16 bf16x4 __attribute__((ext_vector_type(4)));
typedef float f32x4 __attribute__((ext_vector_type(4)));
typedef unsigned int u32;

typedef __attribute__((address_space(1))) const void* as1_cvoid;
typedef __attribute__((address_space(3))) void* as3_void;

__device__ __forceinline__ void gload_lds16(const void* g, void* l) {
  __builtin_amdgcn_global_load_lds((as1_cvoid)g, (as3_void)l, 16, 0, 0);
}

// ---------------- K1: f32 -> bf16 convert (X) ----------------
__global__ void cvt_kernel(const float* __restrict__ src, bf16* __restrict__ dst, int n4) {
  int stride = gridDim.x * blockDim.x;
  for (int i = blockIdx.x * blockDim.x + threadIdx.x; i < n4; i += stride) {
    float4 v = ((const float4*)src)[i];
    bf16x4 o;
    o[0] = (bf16)v.x; o[1] = (bf16)v.y; o[2] = (bf16)v.z; o[3] = (bf16)v.w;
    ((bf16x4*)dst)[i] = o;
  }
}

// ---------------- K1a: 4 weight matrices + mask count in one launch ----------------
__global__ void cvt4_kernel(const float* __restrict__ W0, const float* __restrict__ W1,
                            const float* __restrict__ W2, const float* __restrict__ W3,
                            bf16* __restrict__ D0, bf16* __restrict__ D1,
                            bf16* __restrict__ D2, bf16* __restrict__ D3,
                            const unsigned char* __restrict__ mask, int* __restrict__ nm) {
  if (blockIdx.x == 1024) {  // fused per-batch mask count
    int wid = threadIdx.x >> 6, lane = threadIdx.x & 63;
    if (wid >= BB) return;
    int s = 0;
    for (int i = lane; i < SS; i += 64) s += (mask[wid * SS + i] != 0) ? 1 : 0;
#pragma unroll
    for (int m = 1; m < 64; m <<= 1) s += __shfl_xor(s, m);
    if (lane == 0) nm[wid] = s;
    return;
  }
  int which = blockIdx.x >> 8;  // 4 x 256 blocks
  const float* src = which == 0 ? W0 : which == 1 ? W1 : which == 2 ? W2 : W3;
  bf16* dst = which == 0 ? D0 : which == 1 ? D1 : which == 2 ? D2 : D3;
  const int n4 = DD * DD / 4;
  for (int i = (blockIdx.x & 255) * 256 + threadIdx.x; i < n4; i += 65536) {
    float4 v = ((const float4*)src)[i];
    bf16x4 o;
    o[0] = (bf16)v.x; o[1] = (bf16)v.y; o[2] = (bf16)v.z; o[3] = (bf16)v.w;
    ((bf16x4*)dst)[i] = o;
  }
}

// ---------------- K1b: RoPE sin/cos table ----------------
__global__ void sincos_table_kernel(const int* __restrict__ nm, float2* __restrict__ tbl) {
  int g = blockIdx.x * 256 + threadIdx.x;  // (b*S+s)*32 + j
  int j = g & 31;
  int idx = g >> 5;
  int b = idx >> 11, s = idx & 2047;
  int pos = s - nm[b];
  float inv_ts = __expf((float)j * (-9.210340371976184f / 32.0f));
  float sn, cs;
  sincosf((float)pos * inv_ts, &sn, &cs);
  tbl[g] = make_float2(cs, sn);
}

// ---------------- K2: fused QKV GEMM + RoPE/RMS/scale epilogue (R12 proven) ----------------
__global__ void __launch_bounds__(256) gemm_qkv_kernel(
    const bf16* __restrict__ A, const bf16* __restrict__ Wq, const bf16* __restrict__ Wk,
    const bf16* __restrict__ Wv, const float* __restrict__ qls, const float* __restrict__ kls,
    const float* __restrict__ pds, const float2* __restrict__ tbl,
    bf16* __restrict__ Qp, bf16* __restrict__ Kp, bf16* __restrict__ Vt) {
  __shared__ __align__(16) char smem[4 * 64 * 72 * 2];
  bf16* Ab = (bf16*)smem;
  bf16* Bb = (bf16*)(smem + 8192);
  const int tid = threadIdx.x;
  const int wid = tid >> 6, lane = tid & 63;
  const int lr = lane & 15, lg = lane >> 4;
  const int K = DD;
  const int nx = 24;
  const int cpx = gridDim.x >> 3;
  const int lid = (blockIdx.x & 7) * cpx + (blockIdx.x >> 3);
  const int m0 = (lid / nx) * 128;
  const int ntile = lid % nx;
  const int which = ntile >> 3;
  const int n0 = (ntile & 7) * 128;
  const bf16* Bm = which == 0 ? Wq : (which == 1 ? Wk : Wv);
  const int wm = (wid >> 1) * 64, wn = (wid & 1) * 64;
  f32x4 acc[4][4] = {};
  for (int k0 = 0; k0 < K; k0 += 32) {
    __syncthreads();
#pragma unroll
    for (int i = 0; i < 2; ++i) {
      int o = (wid * 2 + i) * 1024 + lane * 16;
      int row = o >> 6;
      int ke = (o & 63) >> 1;
      gload_lds16(A + (size_t)(m0 + row) * K + k0 + ke, (char*)Ab + o);
      gload_lds16(Bm + (size_t)(n0 + row) * K + k0 + ke, (char*)Bb + o);
    }
    __syncthreads();
    bf16x8 af[4], bf_[4];
#pragma unroll
    for (int i = 0; i < 4; ++i) af[i] = *(const bf16x8*)&Ab[(wm + i * 16 + lr) * 32 + lg * 8];
#pragma unroll
    for (int j = 0; j < 4; ++j) bf_[j] = *(const bf16x8*)&Bb[(wn + j * 16 + lr) * 32 + lg * 8];
#pragma unroll
    for (int i = 0; i < 4; ++i)
#pragma unroll
      for (int j = 0; j < 4; ++j)
        acc[i][j] = __builtin_amdgcn_mfma_f32_16x16x32_bf16(af[i], bf_[j], acc[i][j], 0, 0, 0);
  }
  const int b = m0 >> 11;
  const int s0g = m0 & 2047;
  const int hq = n0 >> 6;
  if (which < 2) {
    float scj[4];
#pragma unroll
    for (int j = 0; j < 4; ++j) {
      int d = j * 16 + lr;
      scj[j] = (which == 0) ? qls[d] * 0.26017112262570096f * log1pf(__expf(pds[d]))
                            : kls[d];
    }
    bf16* Out = which == 0 ? Qp : Kp;
    const int h = hq + (wn >> 6);
    const size_t base = (size_t)(b * 16 + h) * SS;
#pragma unroll
    for (int i = 0; i < 4; ++i)
#pragma unroll
      for (int r = 0; r < 4; ++r) {
        int srow = s0g + wm + i * 16 + lg * 4 + r;
        const float2* trow = tbl + ((size_t)(b * SS + srow) << 5);
        float2 t0 = trow[lr], t1 = trow[16 + lr];
        float a0 = acc[i][0][r], a1 = acc[i][1][r], a2 = acc[i][2][r], a3 = acc[i][3][r];
        float n0_ = a0 * t0.x - a2 * t0.y;
        float n2_ = a2 * t0.x + a0 * t0.y;
        float n1_ = a1 * t1.x - a3 * t1.y;
        float n3_ = a3 * t1.x + a1 * t1.y;
        float ssum = n0_ * n0_ + n1_ * n1_ + n2_ * n2_ + n3_ * n3_;
        ssum += __shfl_xor(ssum, 1);
        ssum += __shfl_xor(ssum, 2);
        ssum += __shfl_xor(ssum, 4);
        ssum += __shfl_xor(ssum, 8);
        float rinv = rsqrtf(ssum * (1.0f / 64.0f) + 1e-6f);
        bf16* orow = Out + (base + srow) * 64;
        orow[lr]      = (bf16)(n0_ * rinv * scj[0]);
        orow[16 + lr] = (bf16)(n1_ * rinv * scj[1]);
        orow[32 + lr] = (bf16)(n2_ * rinv * scj[2]);
        orow[48 + lr] = (bf16)(n3_ * rinv * scj[3]);
      }
  } else {
    __syncthreads();
    bf16* tw = (bf16*)smem + wid * 64 * 72;
#pragma unroll
    for (int i = 0; i < 4; ++i)
#pragma unroll
      for (int j = 0; j < 4; ++j)
#pragma unroll
        for (int r = 0; r < 4; ++r)
          tw[(j * 16 + lr) * 72 + i * 16 + lg * 4 + r] = (bf16)acc[i][j][r];
    __syncthreads();
    int d = tid >> 2, sc = (tid & 3) * 16;
#pragma unroll
    for (int w = 0; w < 4; ++w) {
      int rh = w >> 1, hh = w & 1;
      const bf16* ts = (const bf16*)smem + w * 64 * 72 + d * 72 + sc;
      bf16x8 v0 = *(const bf16x8*)ts;
      bf16x8 v1 = *(const bf16x8*)(ts + 8);
      size_t vo = ((size_t)((b * 16 + hq + hh) * 64 + d)) * SS + s0g + rh * 64 + sc;
      *(bf16x8*)(Vt + vo) = v0;
      *(bf16x8*)(Vt + vo + 8) = v1;
    }
  }
}

// ---------------- K5: C[M,N] = A[M,K] @ B[N,K]^T (f32 out, for Wo) ----------------
__global__ void __launch_bounds__(256) gemm_bt_kernel(const bf16* __restrict__ A,
                                                      const bf16* __restrict__ Bm,
                                                      float* __restrict__ Cout,
                                                      int M, int N, int K) {
  __shared__ bf16 Ab[128 * 32];
  __shared__ bf16 Bb[128 * 32];
  const int tid = threadIdx.x;
  const int wid = tid >> 6, lane = tid & 63;
  const int lr = lane & 15, lg = lane >> 4;
  const int nx = N >> 7;
  const int cpx = gridDim.x >> 3;
  const int lid = (blockIdx.x & 7) * cpx + (blockIdx.x >> 3);
  const int m0 = (lid / nx) * 128, n0 = (lid % nx) * 128;
  const int wm = (wid >> 1) * 64, wn = (wid & 1) * 64;
  f32x4 acc[4][4] = {};
  for (int k0 = 0; k0 < K; k0 += 32) {
    __syncthreads();
#pragma unroll
    for (int i = 0; i < 2; ++i) {
      int o = (wid * 2 + i) * 1024 + lane * 16;
      int row = o >> 6;
      int ke = (o & 63) >> 1;
      gload_lds16(A + (size_t)(m0 + row) * K + k0 + ke, (char*)Ab + o);
      gload_lds16(Bm + (size_t)(n0 + row) * K + k0 + ke, (char*)Bb + o);
    }
    __syncthreads();
    bf16x8 af[4], bf_[4];
#pragma unroll
    for (int i = 0; i < 4; ++i) af[i] = *(const bf16x8*)&Ab[(wm + i * 16 + lr) * 32 + lg * 8];
#pragma unroll
    for (int j = 0; j < 4; ++j) bf_[j] = *(const bf16x8*)&Bb[(wn + j * 16 + lr) * 32 + lg * 8];
#pragma unroll
    for (int i = 0; i < 4; ++i)
#pragma unroll
      for (int j = 0; j < 4; ++j)
        acc[i][j] = __builtin_amdgcn_mfma_f32_16x16x32_bf16(af[i], bf_[j], acc[i][j], 0, 0, 0);
  }
#pragma unroll
  for (int i = 0; i < 4; ++i)
#pragma unroll
    for (int j = 0; j < 4; ++j)
#pragma unroll
      for (int r = 0; r < 4; ++r) {
        int row = m0 + wm + i * 16 + lg * 4 + r;
        int col = n0 + wn + j * 16 + lr;
        Cout[(size_t)row * N + col] = acc[i][j][r];
      }
}

// ---------------- K4: causal flash attention (R12 structure + magic-square px) ----------------
// px chosen so the 4 co-resident blocks on each CU (bid ≡ c mod 256) get px sets
// {0,5,10,15}/{1,4,11,14}/{2,7,8,13}/{3,6,9,12} — each sums 30, so per-CU total
// loop iterations (Σnt = 128-Σpx = 98) are EQUAL across CUs (was 92..104 spread).
// Bijective over (bh, px). Purely a speed heuristic; correctness order-free.
__global__ void __launch_bounds__(256, 2) flash_kernel(
    const bf16* __restrict__ Qp, const bf16* __restrict__ Kp, const bf16* __restrict__ Vt,
    bf16* __restrict__ O, const int* __restrict__ nm) {
  __shared__ bf16 Kb[2][64 * 64];
  __shared__ bf16 Vb[64 * 64];
  __shared__ u32 Pl[4][16][32];
  const int c = blockIdx.x & 255;
  const int k4 = blockIdx.x >> 8;  // co-resident index 0..3
  const int bh = c & 63;
  const int p0 = c >> 6;
  const unsigned long long MAGIC = 0xC963D872EB41FA50ull;  // nibble i=p0*4+k4 -> px
  const int px = (int)((MAGIC >> ((p0 * 4 + k4) * 4)) & 0xF);
  const int xA = 31 - px, xB = px;
  const int b = bh >> 4, h = bh & 15;
  const int tid = threadIdx.x;
  const int wid = tid >> 6, lane = tid & 63;
  const int lr = lane & 15, lg = lane >> 4;
  const int sw = (lr & 7) << 2;
  const int nmb = nm[b];
  const int wqA = xA * 64 + wid * 16;
  const int wqB = xB * 64 + wid * 16;
  const int nt = xA + 1;

  const int koffA = lr * 128 + ((lg ^ (lr & 7)) << 4);
  const int koffB = lr * 128 + (((4 + lg) ^ (lr & 7)) << 4);
  const int o0 = tid * 16, o1 = 4096 + tid * 16;
  const int r0 = o0 >> 7, r1 = o1 >> 7;
  const int c0 = ((o0 >> 4) & 7) ^ (r0 & 7), c1 = ((o1 >> 4) & 7) ^ (r1 & 7);
  const bf16* kg0 = Kp + (size_t)bh * (SS * 64) + r0 * 64 + c0 * 8;
  const bf16* kg1 = Kp + (size_t)bh * (SS * 64) + r1 * 64 + c1 * 8;
  const bf16* vg0 = Vt + (size_t)bh * (SS * 64) + (size_t)r0 * SS + c0 * 8;
  const bf16* vg1 = Vt + (size_t)bh * (SS * 64) + (size_t)r1 * SS + c1 * 8;
  char* kl0 = (char*)&Kb[0][0] + o0;
  char* kl1 = (char*)&Kb[0][0] + o1;
  char* vl0 = (char*)Vb + o0;
  char* vl1 = (char*)Vb + o1;
  u32* plw = &Pl[wid][lr][0];

  bf16x8 qfA[2], qfB[2];
#pragma unroll
  for (int kh = 0; kh < 2; ++kh) {
    qfA[kh] = *(const bf16x8*)(Qp + ((size_t)bh * SS + wqA + lr) * 64 + kh * 32 + lg * 8);
    qfB[kh] = *(const bf16x8*)(Qp + ((size_t)bh * SS + wqB + lr) * 64 + kh * 32 + lg * 8);
  }

  float mA = -1e30f, lA = 0.f, mB = -1e30f, lB = 0.f;
  f32x4 oA[4] = {}, oB[4] = {};

  auto STAGE_K = [&](int bi, int t) {
    gload_lds16(kg0 + (size_t)t * 4096, kl0 + bi * 8192);
    gload_lds16(kg1 + (size_t)t * 4096, kl1 + bi * 8192);
  };
  auto STAGE_V = [&](int t) {
    gload_lds16(vg0 + t * 64, vl0);
    gload_lds16(vg1 + t * 64, vl1);
  };

  STAGE_K(0, 0);
  STAGE_V(0);
  __syncthreads();
  int buf = 0;
  for (int t = 0; t < nt; ++t) {
    const int kv0 = t * 64;
    if (t + 1 < nt) STAGE_K(buf ^ 1, t + 1);
    const bool actB = (t <= xB);
    f32x4 sA[4], sB[4];

    const char* kbb = (const char*)&Kb[0][0] + buf * 8192;
    __builtin_amdgcn_s_setprio(1);
#pragma unroll
    for (int j = 0; j < 4; ++j) {
      bf16x8 kf0 = *(const bf16x8*)(kbb + koffA + j * 2048);
      bf16x8 kf1 = *(const bf16x8*)(kbb + koffB + j * 2048);
      f32x4 z = {};
      z = __builtin_amdgcn_mfma_f32_16x16x32_bf16(kf0, qfA[0], z, 0, 0, 0);
      z = __builtin_amdgcn_mfma_f32_16x16x32_bf16(kf1, qfA[1], z, 0, 0, 0);
      sA[j] = z;
      if (actB) {
        f32x4 z2 = {};
        z2 = __builtin_amdgcn_mfma_f32_16x16x32_bf16(kf0, qfB[0], z2, 0, 0, 0);
        z2 = __builtin_amdgcn_mfma_f32_16x16x32_bf16(kf1, qfB[1], z2, 0, 0, 0);
        sB[j] = z2;
      }
    }
    __builtin_amdgcn_s_setprio(0);

    auto SOFTMAX = [&](f32x4* s, float& m_r, float& l_pp, f32x4* oacc, bf16x8* pb,
                       int xS, int wqS) {
      if (t == xS) {
        int qr = wqS + lr;
#pragma unroll
        for (int j = 0; j < 4; ++j) {
          int kvb = kv0 + j * 16 + lg * 4;
#pragma unroll
          for (int r = 0; r < 4; ++r)
            if (kvb + r > qr) s[j][r] = -1e30f;
        }
      }
      if (kv0 < nmb) {
#pragma unroll
        for (int j = 0; j < 4; ++j) {
          int kvb = kv0 + j * 16 + lg * 4;
#pragma unroll
          for (int r = 0; r < 4; ++r)
            if (kvb + r < nmb) s[j][r] = -1e30f;
        }
      }
      float t0 = fmaxf(fmaxf(s[0][0], s[0][1]), s[0][2]);
      float t1 = fmaxf(fmaxf(s[0][3], s[1][0]), s[1][1]);
      float t2 = fmaxf(fmaxf(s[1][2], s[1][3]), s[2][0]);
      float t3 = fmaxf(fmaxf(s[2][1], s[2][2]), s[2][3]);
      float t4 = fmaxf(fmaxf(s[3][0], s[3][1]), s[3][2]);
      float t5 = fmaxf(fmaxf(t0, t1), s[3][3]);
      float pm = fmaxf(fmaxf(t2, t3), fmaxf(t4, t5));
      if (!__all(pm - m_r <= 8.f)) {
        pm = fmaxf(pm, __shfl_xor(pm, 16));
        pm = fmaxf(pm, __shfl_xor(pm, 32));
        float mn = fmaxf(m_r, pm);
        float scl = exp2f(m_r - mn);
        m_r = mn;
        l_pp *= scl;
        f32x4 sv = {scl, scl, scl, scl};
#pragma unroll
        for (int jd = 0; jd < 4; ++jd) oacc[jd] *= sv;
      }
      const float mloc = m_r;
      float lp = l_pp;
#pragma unroll
      for (int j = 0; j < 4; ++j) {
        float p0_ = exp2f(s[j][0] - mloc), p1_ = exp2f(s[j][1] - mloc);
        float p2_ = exp2f(s[j][2] - mloc), p3_ = exp2f(s[j][3] - mloc);
        lp += (p0_ + p1_) + (p2_ + p3_);
        union { bf16 hx[4]; uint2 u2; } pk;
        pk.hx[0] = (bf16)p0_; pk.hx[1] = (bf16)p1_;
        pk.hx[2] = (bf16)p2_; pk.hx[3] = (bf16)p3_;
        *(uint2*)&plw[(j * 8 + lg * 2) ^ sw] = pk.u2;
      }
      l_pp = lp;
#pragma unroll
      for (int kh = 0; kh < 2; ++kh)
        pb[kh] = *(const bf16x8*)&plw[(kh * 16 + lg * 4) ^ sw];
    };

    bf16x8 pbA[2], pbB[2];
    SOFTMAX(sA, mA, lA, oA, pbA, xA, wqA);
    if (actB) SOFTMAX(sB, mB, lB, oB, pbB, xB, wqB);

    if (t > 0) {
      if (t + 1 < nt)
        asm volatile("s_waitcnt vmcnt(2)" ::: "memory");
      else
        asm volatile("s_waitcnt vmcnt(0)" ::: "memory");
      __builtin_amdgcn_s_barrier();
      __builtin_amdgcn_sched_barrier(0);
    }
    __builtin_amdgcn_s_setprio(1);
#pragma unroll
    for (int jd = 0; jd < 4; ++jd) {
      bf16x8 va0 = *(const bf16x8*)((const char*)Vb + koffA + jd * 2048);
      bf16x8 va1 = *(const bf16x8*)((const char*)Vb + koffB + jd * 2048);
      oA[jd] = __builtin_amdgcn_mfma_f32_16x16x32_bf16(va0, pbA[0], oA[jd], 0, 0, 0);
      oA[jd] = __builtin_amdgcn_mfma_f32_16x16x32_bf16(va1, pbA[1], oA[jd], 0, 0, 0);
      if (actB) {
        oB[jd] = __builtin_amdgcn_mfma_f32_16x16x32_bf16(va0, pbB[0], oB[jd], 0, 0, 0);
        oB[jd] = __builtin_amdgcn_mfma_f32_16x16x32_bf16(va1, pbB[1], oB[jd], 0, 0, 0);
      }
    }
    __builtin_amdgcn_s_setprio(0);
    __syncthreads();
    if (t + 1 < nt) STAGE_V(t + 1);
    buf ^= 1;
  }
#pragma unroll
  for (int st = 0; st < 2; ++st) {
    float l = st == 0 ? lA : lB;
    const f32x4* oacc = st == 0 ? oA : oB;
    int wq = st == 0 ? wqA : wqB;
    l += __shfl_xor(l, 16);
    l += __shfl_xor(l, 32);
    float invl = 1.0f / l;
    size_t rowoff = ((size_t)b * SS + wq + lr) * DD + h * 64;
#pragma unroll
    for (int jd = 0; jd < 4; ++jd) {
      f32x4 ov = oacc[jd] * invl;
      bf16x4 hv;
      hv[0] = (bf16)ov[0]; hv[1] = (bf16)ov[1]; hv[2] = (bf16)ov[2]; hv[3] = (bf16)ov[3];
      *(bf16x4*)(O + rowoff + jd * 16 + lg * 4) = hv;
    }
  }
}

// ---------------- host launch ----------------
extern "C" void kernel_launch(void* const* d_in, const int* in_sizes, int n_in,
                              void* d_out, int out_size, void* d_ws, size_t ws_size,
                              hipStream_t stream) {
  const float* X = (const float*)d_in[0];
  const float* Wq = (const float*)d_in[1];
  const float* Wk = (const float*)d_in[2];
  const float* Wv = (const float*)d_in[3];
  const float* Wo = (const float*)d_in[4];
  const float* qls = (const float*)d_in[5];
  const float* kls = (const float*)d_in[6];
  const float* pds = (const float*)d_in[7];
  const unsigned char* mask = (const unsigned char*)d_in[8];

  char* ws = (char*)d_ws;
  size_t off = 0;
  auto alloc = [&](size_t bytes) {
    char* p = ws + off;
    off += (bytes + 255) & ~(size_t)255;
    return p;
  };
  const size_t NTOK = (size_t)BB * SS;  // 8192
  int* nm = (int*)alloc(16);
  bf16* Xb = (bf16*)alloc(NTOK * DD * 2);
  bf16* Wqb = (bf16*)alloc((size_t)DD * DD * 2);
  bf16* Wkb = (bf16*)alloc((size_t)DD * DD * 2);
  bf16* Wvb = (bf16*)alloc((size_t)DD * DD * 2);
  bf16* Wob = (bf16*)alloc((size_t)DD * DD * 2);
  bf16* Qp = (bf16*)alloc(NTOK * DD * 2);
  bf16* Kp = (bf16*)alloc(NTOK * DD * 2);
  bf16* Vt = (bf16*)alloc(NTOK * DD * 2);
  float2* tbl = (float2*)alloc(NTOK * 32 * sizeof(float2));
  bf16* Oat = Xb;  // alias: Xb dead after fused QKV GEMM

  cvt_kernel<<<1024, 256, 0, stream>>>(X, Xb, (int)(NTOK * DD / 4));
  cvt4_kernel<<<1025, 256, 0, stream>>>(Wq, Wk, Wv, Wo, Wqb, Wkb, Wvb, Wob, mask, nm);
  sincos_table_kernel<<<1024, 256, 0, stream>>>(nm, tbl);

  gemm_qkv_kernel<<<(int)(NTOK / 128) * 24, 256, 0, stream>>>(Xb, Wqb, Wkb, Wvb, qls, kls, pds,
                                                              tbl, Qp, Kp, Vt);
  flash_kernel<<<1024, 256, 0, stream>>>(Qp, Kp, Vt, Oat, nm);
  gemm_bt_kernel<<<(int)(NTOK / 128) * (DD / 128), 256, 0, stream>>>(Oat, Wob, (float*)d_out,
                                                                     (int)NTOK, DD, DD);
}

// Round 16
// 192.455 us; speedup vs baseline: 1.1712x; 1.0445x over previous
//
#include <hip/hip_runtime.h>
#include <cstdint>
#include <cstddef>

#define BB 4
#define SS 2048
#define DD 1024
#define HH 16

typedef __bf16 bf16;
typedef __bf16 bf16x8 __attribute__((ext_vector_type(8)));
typedef __bf16 bf16x4 __attribute__((ext_vector_type(4)));
typedef float f32x4 __attribute__((ext_vector_type(4)));
typedef unsigned int u32;

typedef __attribute__((address_space(1))) const void* as1_cvoid;
typedef __attribute__((address_space(3))) void* as3_void;

__device__ __forceinline__ void gload_lds16(const void* g, void* l) {
  __builtin_amdgcn_global_load_lds((as1_cvoid)g, (as3_void)l, 16, 0, 0);
}

// ---------------- K1: f32 -> bf16 convert (X) ----------------
__global__ void cvt_kernel(const float* __restrict__ src, bf16* __restrict__ dst, int n4) {
  int stride = gridDim.x * blockDim.x;
  for (int i = blockIdx.x * blockDim.x + threadIdx.x; i < n4; i += stride) {
    float4 v = ((const float4*)src)[i];
    bf16x4 o;
    o[0] = (bf16)v.x; o[1] = (bf16)v.y; o[2] = (bf16)v.z; o[3] = (bf16)v.w;
    ((bf16x4*)dst)[i] = o;
  }
}

// ---------------- K1a: 4 weight matrices + mask count in one launch ----------------
__global__ void cvt4_kernel(const float* __restrict__ W0, const float* __restrict__ W1,
                            const float* __restrict__ W2, const float* __restrict__ W3,
                            bf16* __restrict__ D0, bf16* __restrict__ D1,
                            bf16* __restrict__ D2, bf16* __restrict__ D3,
                            const unsigned char* __restrict__ mask, int* __restrict__ nm) {
  if (blockIdx.x == 1024) {  // fused per-batch mask count
    int wid = threadIdx.x >> 6, lane = threadIdx.x & 63;
    if (wid >= BB) return;
    int s = 0;
    for (int i = lane; i < SS; i += 64) s += (mask[wid * SS + i] != 0) ? 1 : 0;
#pragma unroll
    for (int m = 1; m < 64; m <<= 1) s += __shfl_xor(s, m);
    if (lane == 0) nm[wid] = s;
    return;
  }
  int which = blockIdx.x >> 8;  // 4 x 256 blocks
  const float* src = which == 0 ? W0 : which == 1 ? W1 : which == 2 ? W2 : W3;
  bf16* dst = which == 0 ? D0 : which == 1 ? D1 : which == 2 ? D2 : D3;
  const int n4 = DD * DD / 4;
  for (int i = (blockIdx.x & 255) * 256 + threadIdx.x; i < n4; i += 65536) {
    float4 v = ((const float4*)src)[i];
    bf16x4 o;
    o[0] = (bf16)v.x; o[1] = (bf16)v.y; o[2] = (bf16)v.z; o[3] = (bf16)v.w;
    ((bf16x4*)dst)[i] = o;
  }
}

// ---------------- K1b: RoPE sin/cos table ----------------
__global__ void sincos_table_kernel(const int* __restrict__ nm, float2* __restrict__ tbl) {
  int g = blockIdx.x * 256 + threadIdx.x;  // (b*S+s)*32 + j
  int j = g & 31;
  int idx = g >> 5;
  int b = idx >> 11, s = idx & 2047;
  int pos = s - nm[b];
  float inv_ts = __expf((float)j * (-9.210340371976184f / 32.0f));
  float sn, cs;
  sincosf((float)pos * inv_ts, &sn, &cs);
  tbl[g] = make_float2(cs, sn);
}

// ---------------- K2: fused QKV GEMM + RoPE/RMS/scale epilogue (R12 proven) ----------------
__global__ void __launch_bounds__(256) gemm_qkv_kernel(
    const bf16* __restrict__ A, const bf16* __restrict__ Wq, const bf16* __restrict__ Wk,
    const bf16* __restrict__ Wv, const float* __restrict__ qls, const float* __restrict__ kls,
    const float* __restrict__ pds, const float2* __restrict__ tbl,
    bf16* __restrict__ Qp, bf16* __restrict__ Kp, bf16* __restrict__ Vt) {
  __shared__ __align__(16) char smem[4 * 64 * 72 * 2];
  bf16* Ab = (bf16*)smem;
  bf16* Bb = (bf16*)(smem + 8192);
  const int tid = threadIdx.x;
  const int wid = tid >> 6, lane = tid & 63;
  const int lr = lane & 15, lg = lane >> 4;
  const int K = DD;
  const int nx = 24;
  const int cpx = gridDim.x >> 3;
  const int lid = (blockIdx.x & 7) * cpx + (blockIdx.x >> 3);
  const int m0 = (lid / nx) * 128;
  const int ntile = lid % nx;
  const int which = ntile >> 3;
  const int n0 = (ntile & 7) * 128;
  const bf16* Bm = which == 0 ? Wq : (which == 1 ? Wk : Wv);
  const int wm = (wid >> 1) * 64, wn = (wid & 1) * 64;
  f32x4 acc[4][4] = {};
  for (int k0 = 0; k0 < K; k0 += 32) {
    __syncthreads();
#pragma unroll
    for (int i = 0; i < 2; ++i) {
      int o = (wid * 2 + i) * 1024 + lane * 16;
      int row = o >> 6;
      int ke = (o & 63) >> 1;
      gload_lds16(A + (size_t)(m0 + row) * K + k0 + ke, (char*)Ab + o);
      gload_lds16(Bm + (size_t)(n0 + row) * K + k0 + ke, (char*)Bb + o);
    }
    __syncthreads();
    bf16x8 af[4], bf_[4];
#pragma unroll
    for (int i = 0; i < 4; ++i) af[i] = *(const bf16x8*)&Ab[(wm + i * 16 + lr) * 32 + lg * 8];
#pragma unroll
    for (int j = 0; j < 4; ++j) bf_[j] = *(const bf16x8*)&Bb[(wn + j * 16 + lr) * 32 + lg * 8];
#pragma unroll
    for (int i = 0; i < 4; ++i)
#pragma unroll
      for (int j = 0; j < 4; ++j)
        acc[i][j] = __builtin_amdgcn_mfma_f32_16x16x32_bf16(af[i], bf_[j], acc[i][j], 0, 0, 0);
  }
  const int b = m0 >> 11;
  const int s0g = m0 & 2047;
  const int hq = n0 >> 6;
  if (which < 2) {
    float scj[4];
#pragma unroll
    for (int j = 0; j < 4; ++j) {
      int d = j * 16 + lr;
      scj[j] = (which == 0) ? qls[d] * 0.26017112262570096f * log1pf(__expf(pds[d]))
                            : kls[d];
    }
    bf16* Out = which == 0 ? Qp : Kp;
    const int h = hq + (wn >> 6);
    const size_t base = (size_t)(b * 16 + h) * SS;
#pragma unroll
    for (int i = 0; i < 4; ++i)
#pragma unroll
      for (int r = 0; r < 4; ++r) {
        int srow = s0g + wm + i * 16 + lg * 4 + r;
        const float2* trow = tbl + ((size_t)(b * SS + srow) << 5);
        float2 t0 = trow[lr], t1 = trow[16 + lr];
        float a0 = acc[i][0][r], a1 = acc[i][1][r], a2 = acc[i][2][r], a3 = acc[i][3][r];
        float n0_ = a0 * t0.x - a2 * t0.y;
        float n2_ = a2 * t0.x + a0 * t0.y;
        float n1_ = a1 * t1.x - a3 * t1.y;
        float n3_ = a3 * t1.x + a1 * t1.y;
        float ssum = n0_ * n0_ + n1_ * n1_ + n2_ * n2_ + n3_ * n3_;
        ssum += __shfl_xor(ssum, 1);
        ssum += __shfl_xor(ssum, 2);
        ssum += __shfl_xor(ssum, 4);
        ssum += __shfl_xor(ssum, 8);
        float rinv = rsqrtf(ssum * (1.0f / 64.0f) + 1e-6f);
        bf16* orow = Out + (base + srow) * 64;
        orow[lr]      = (bf16)(n0_ * rinv * scj[0]);
        orow[16 + lr] = (bf16)(n1_ * rinv * scj[1]);
        orow[32 + lr] = (bf16)(n2_ * rinv * scj[2]);
        orow[48 + lr] = (bf16)(n3_ * rinv * scj[3]);
      }
  } else {
    __syncthreads();
    bf16* tw = (bf16*)smem + wid * 64 * 72;
#pragma unroll
    for (int i = 0; i < 4; ++i)
#pragma unroll
      for (int j = 0; j < 4; ++j)
#pragma unroll
        for (int r = 0; r < 4; ++r)
          tw[(j * 16 + lr) * 72 + i * 16 + lg * 4 + r] = (bf16)acc[i][j][r];
    __syncthreads();
    int d = tid >> 2, sc = (tid & 3) * 16;
#pragma unroll
    for (int w = 0; w < 4; ++w) {
      int rh = w >> 1, hh = w & 1;
      const bf16* ts = (const bf16*)smem + w * 64 * 72 + d * 72 + sc;
      bf16x8 v0 = *(const bf16x8*)ts;
      bf16x8 v1 = *(const bf16x8*)(ts + 8);
      size_t vo = ((size_t)((b * 16 + hq + hh) * 64 + d)) * SS + s0g + rh * 64 + sc;
      *(bf16x8*)(Vt + vo) = v0;
      *(bf16x8*)(Vt + vo + 8) = v1;
    }
  }
}

// ---------------- K5: C[M,N] = A[M,K] @ B[N,K]^T (f32 out, for Wo) ----------------
__global__ void __launch_bounds__(256) gemm_bt_kernel(const bf16* __restrict__ A,
                                                      const bf16* __restrict__ Bm,
                                                      float* __restrict__ Cout,
                                                      int M, int N, int K) {
  __shared__ bf16 Ab[128 * 32];
  __shared__ bf16 Bb[128 * 32];
  const int tid = threadIdx.x;
  const int wid = tid >> 6, lane = tid & 63;
  const int lr = lane & 15, lg = lane >> 4;
  const int nx = N >> 7;
  const int cpx = gridDim.x >> 3;
  const int lid = (blockIdx.x & 7) * cpx + (blockIdx.x >> 3);
  const int m0 = (lid / nx) * 128, n0 = (lid % nx) * 128;
  const int wm = (wid >> 1) * 64, wn = (wid & 1) * 64;
  f32x4 acc[4][4] = {};
  for (int k0 = 0; k0 < K; k0 += 32) {
    __syncthreads();
#pragma unroll
    for (int i = 0; i < 2; ++i) {
      int o = (wid * 2 + i) * 1024 + lane * 16;
      int row = o >> 6;
      int ke = (o & 63) >> 1;
      gload_lds16(A + (size_t)(m0 + row) * K + k0 + ke, (char*)Ab + o);
      gload_lds16(Bm + (size_t)(n0 + row) * K + k0 + ke, (char*)Bb + o);
    }
    __syncthreads();
    bf16x8 af[4], bf_[4];
#pragma unroll
    for (int i = 0; i < 4; ++i) af[i] = *(const bf16x8*)&Ab[(wm + i * 16 + lr) * 32 + lg * 8];
#pragma unroll
    for (int j = 0; j < 4; ++j) bf_[j] = *(const bf16x8*)&Bb[(wn + j * 16 + lr) * 32 + lg * 8];
#pragma unroll
    for (int i = 0; i < 4; ++i)
#pragma unroll
      for (int j = 0; j < 4; ++j)
        acc[i][j] = __builtin_amdgcn_mfma_f32_16x16x32_bf16(af[i], bf_[j], acc[i][j], 0, 0, 0);
  }
#pragma unroll
  for (int i = 0; i < 4; ++i)
#pragma unroll
    for (int j = 0; j < 4; ++j)
#pragma unroll
      for (int r = 0; r < 4; ++r) {
        int row = m0 + wm + i * 16 + lg * 4 + r;
        int col = n0 + wn + j * 16 + lr;
        Cout[(size_t)row * N + col] = acc[i][j][r];
      }
}

// ---------------- K4: causal flash attention (R12 exact: bh=bid&63, px=bid>>6) ----------------
// px=bid>>6: deepest blocks (px=0 -> nt=32) dispatch FIRST (natural LPT; R15's
// magic-square remap scattered deep blocks into the tail and cost +7.5us).
__global__ void __launch_bounds__(256, 2) flash_kernel(
    const bf16* __restrict__ Qp, const bf16* __restrict__ Kp, const bf16* __restrict__ Vt,
    bf16* __restrict__ O, const int* __restrict__ nm) {
  __shared__ bf16 Kb[2][64 * 64];
  __shared__ bf16 Vb[64 * 64];
  __shared__ u32 Pl[4][16][32];
  const int bh = blockIdx.x & 63;
  const int px = blockIdx.x >> 6;  // 0..15
  const int xA = 31 - px, xB = px;
  const int b = bh >> 4, h = bh & 15;
  const int tid = threadIdx.x;
  const int wid = tid >> 6, lane = tid & 63;
  const int lr = lane & 15, lg = lane >> 4;
  const int sw = (lr & 7) << 2;
  const int nmb = nm[b];
  const int wqA = xA * 64 + wid * 16;
  const int wqB = xB * 64 + wid * 16;
  const int nt = xA + 1;

  const int koffA = lr * 128 + ((lg ^ (lr & 7)) << 4);
  const int koffB = lr * 128 + (((4 + lg) ^ (lr & 7)) << 4);
  const int o0 = tid * 16, o1 = 4096 + tid * 16;
  const int r0 = o0 >> 7, r1 = o1 >> 7;
  const int c0 = ((o0 >> 4) & 7) ^ (r0 & 7), c1 = ((o1 >> 4) & 7) ^ (r1 & 7);
  const bf16* kg0 = Kp + (size_t)bh * (SS * 64) + r0 * 64 + c0 * 8;
  const bf16* kg1 = Kp + (size_t)bh * (SS * 64) + r1 * 64 + c1 * 8;
  const bf16* vg0 = Vt + (size_t)bh * (SS * 64) + (size_t)r0 * SS + c0 * 8;
  const bf16* vg1 = Vt + (size_t)bh * (SS * 64) + (size_t)r1 * SS + c1 * 8;
  char* kl0 = (char*)&Kb[0][0] + o0;
  char* kl1 = (char*)&Kb[0][0] + o1;
  char* vl0 = (char*)Vb + o0;
  char* vl1 = (char*)Vb + o1;
  u32* plw = &Pl[wid][lr][0];

  bf16x8 qfA[2], qfB[2];
#pragma unroll
  for (int kh = 0; kh < 2; ++kh) {
    qfA[kh] = *(const bf16x8*)(Qp + ((size_t)bh * SS + wqA + lr) * 64 + kh * 32 + lg * 8);
    qfB[kh] = *(const bf16x8*)(Qp + ((size_t)bh * SS + wqB + lr) * 64 + kh * 32 + lg * 8);
  }

  float mA = -1e30f, lA = 0.f, mB = -1e30f, lB = 0.f;
  f32x4 oA[4] = {}, oB[4] = {};

  auto STAGE_K = [&](int bi, int t) {
    gload_lds16(kg0 + (size_t)t * 4096, kl0 + bi * 8192);
    gload_lds16(kg1 + (size_t)t * 4096, kl1 + bi * 8192);
  };
  auto STAGE_V = [&](int t) {
    gload_lds16(vg0 + t * 64, vl0);
    gload_lds16(vg1 + t * 64, vl1);
  };

  STAGE_K(0, 0);
  STAGE_V(0);
  __syncthreads();
  int buf = 0;
  for (int t = 0; t < nt; ++t) {
    const int kv0 = t * 64;
    if (t + 1 < nt) STAGE_K(buf ^ 1, t + 1);
    const bool actB = (t <= xB);
    f32x4 sA[4], sB[4];

    const char* kbb = (const char*)&Kb[0][0] + buf * 8192;
    __builtin_amdgcn_s_setprio(1);
#pragma unroll
    for (int j = 0; j < 4; ++j) {
      bf16x8 kf0 = *(const bf16x8*)(kbb + koffA + j * 2048);
      bf16x8 kf1 = *(const bf16x8*)(kbb + koffB + j * 2048);
      f32x4 z = {};
      z = __builtin_amdgcn_mfma_f32_16x16x32_bf16(kf0, qfA[0], z, 0, 0, 0);
      z = __builtin_amdgcn_mfma_f32_16x16x32_bf16(kf1, qfA[1], z, 0, 0, 0);
      sA[j] = z;
      if (actB) {
        f32x4 z2 = {};
        z2 = __builtin_amdgcn_mfma_f32_16x16x32_bf16(kf0, qfB[0], z2, 0, 0, 0);
        z2 = __builtin_amdgcn_mfma_f32_16x16x32_bf16(kf1, qfB[1], z2, 0, 0, 0);
        sB[j] = z2;
      }
    }
    __builtin_amdgcn_s_setprio(0);

    auto SOFTMAX = [&](f32x4* s, float& m_r, float& l_pp, f32x4* oacc, bf16x8* pb,
                       int xS, int wqS) {
      if (t == xS) {
        int qr = wqS + lr;
#pragma unroll
        for (int j = 0; j < 4; ++j) {
          int kvb = kv0 + j * 16 + lg * 4;
#pragma unroll
          for (int r = 0; r < 4; ++r)
            if (kvb + r > qr) s[j][r] = -1e30f;
        }
      }
      if (kv0 < nmb) {
#pragma unroll
        for (int j = 0; j < 4; ++j) {
          int kvb = kv0 + j * 16 + lg * 4;
#pragma unroll
          for (int r = 0; r < 4; ++r)
            if (kvb + r < nmb) s[j][r] = -1e30f;
        }
      }
      float t0 = fmaxf(fmaxf(s[0][0], s[0][1]), s[0][2]);
      float t1 = fmaxf(fmaxf(s[0][3], s[1][0]), s[1][1]);
      float t2 = fmaxf(fmaxf(s[1][2], s[1][3]), s[2][0]);
      float t3 = fmaxf(fmaxf(s[2][1], s[2][2]), s[2][3]);
      float t4 = fmaxf(fmaxf(s[3][0], s[3][1]), s[3][2]);
      float t5 = fmaxf(fmaxf(t0, t1), s[3][3]);
      float pm = fmaxf(fmaxf(t2, t3), fmaxf(t4, t5));
      if (!__all(pm - m_r <= 8.f)) {
        pm = fmaxf(pm, __shfl_xor(pm, 16));
        pm = fmaxf(pm, __shfl_xor(pm, 32));
        float mn = fmaxf(m_r, pm);
        float scl = exp2f(m_r - mn);
        m_r = mn;
        l_pp *= scl;
        f32x4 sv = {scl, scl, scl, scl};
#pragma unroll
        for (int jd = 0; jd < 4; ++jd) oacc[jd] *= sv;
      }
      const float mloc = m_r;
      float lp = l_pp;
#pragma unroll
      for (int j = 0; j < 4; ++j) {
        float p0 = exp2f(s[j][0] - mloc), p1 = exp2f(s[j][1] - mloc);
        float p2 = exp2f(s[j][2] - mloc), p3 = exp2f(s[j][3] - mloc);
        lp += (p0 + p1) + (p2 + p3);
        union { bf16 hx[4]; uint2 u2; } pk;
        pk.hx[0] = (bf16)p0; pk.hx[1] = (bf16)p1;
        pk.hx[2] = (bf16)p2; pk.hx[3] = (bf16)p3;
        *(uint2*)&plw[(j * 8 + lg * 2) ^ sw] = pk.u2;
      }
      l_pp = lp;
#pragma unroll
      for (int kh = 0; kh < 2; ++kh)
        pb[kh] = *(const bf16x8*)&plw[(kh * 16 + lg * 4) ^ sw];
    };

    bf16x8 pbA[2], pbB[2];
    SOFTMAX(sA, mA, lA, oA, pbA, xA, wqA);
    if (actB) SOFTMAX(sB, mB, lB, oB, pbB, xB, wqB);

    if (t > 0) {
      if (t + 1 < nt)
        asm volatile("s_waitcnt vmcnt(2)" ::: "memory");
      else
        asm volatile("s_waitcnt vmcnt(0)" ::: "memory");
      __builtin_amdgcn_s_barrier();
      __builtin_amdgcn_sched_barrier(0);
    }
    __builtin_amdgcn_s_setprio(1);
#pragma unroll
    for (int jd = 0; jd < 4; ++jd) {
      bf16x8 va0 = *(const bf16x8*)((const char*)Vb + koffA + jd * 2048);
      bf16x8 va1 = *(const bf16x8*)((const char*)Vb + koffB + jd * 2048);
      oA[jd] = __builtin_amdgcn_mfma_f32_16x16x32_bf16(va0, pbA[0], oA[jd], 0, 0, 0);
      oA[jd] = __builtin_amdgcn_mfma_f32_16x16x32_bf16(va1, pbA[1], oA[jd], 0, 0, 0);
      if (actB) {
        oB[jd] = __builtin_amdgcn_mfma_f32_16x16x32_bf16(va0, pbB[0], oB[jd], 0, 0, 0);
        oB[jd] = __builtin_amdgcn_mfma_f32_16x16x32_bf16(va1, pbB[1], oB[jd], 0, 0, 0);
      }
    }
    __builtin_amdgcn_s_setprio(0);
    __syncthreads();
    if (t + 1 < nt) STAGE_V(t + 1);
    buf ^= 1;
  }
#pragma unroll
  for (int st = 0; st < 2; ++st) {
    float l = st == 0 ? lA : lB;
    const f32x4* oacc = st == 0 ? oA : oB;
    int wq = st == 0 ? wqA : wqB;
    l += __shfl_xor(l, 16);
    l += __shfl_xor(l, 32);
    float invl = 1.0f / l;
    size_t rowoff = ((size_t)b * SS + wq + lr) * DD + h * 64;
#pragma unroll
    for (int jd = 0; jd < 4; ++jd) {
      f32x4 ov = oacc[jd] * invl;
      bf16x4 hv;
      hv[0] = (bf16)ov[0]; hv[1] = (bf16)ov[1]; hv[2] = (bf16)ov[2]; hv[3] = (bf16)ov[3];
      *(bf16x4*)(O + rowoff + jd * 16 + lg * 4) = hv;
    }
  }
}

// ---------------- host launch ----------------
extern "C" void kernel_launch(void* const* d_in, const int* in_sizes, int n_in,
                              void* d_out, int out_size, void* d_ws, size_t ws_size,
                              hipStream_t stream) {
  const float* X = (const float*)d_in[0];
  const float* Wq = (const float*)d_in[1];
  const float* Wk = (const float*)d_in[2];
  const float* Wv = (const float*)d_in[3];
  const float* Wo = (const float*)d_in[4];
  const float* qls = (const float*)d_in[5];
  const float* kls = (const float*)d_in[6];
  const float* pds = (const float*)d_in[7];
  const unsigned char* mask = (const unsigned char*)d_in[8];

  char* ws = (char*)d_ws;
  size_t off = 0;
  auto alloc = [&](size_t bytes) {
    char* p = ws + off;
    off += (bytes + 255) & ~(size_t)255;
    return p;
  };
  const size_t NTOK = (size_t)BB * SS;  // 8192
  int* nm = (int*)alloc(16);
  bf16* Xb = (bf16*)alloc(NTOK * DD * 2);
  bf16* Wqb = (bf16*)alloc((size_t)DD * DD * 2);
  bf16* Wkb = (bf16*)alloc((size_t)DD * DD * 2);
  bf16* Wvb = (bf16*)alloc((size_t)DD * DD * 2);
  bf16* Wob = (bf16*)alloc((size_t)DD * DD * 2);
  bf16* Qp = (bf16*)alloc(NTOK * DD * 2);
  bf16* Kp = (bf16*)alloc(NTOK * DD * 2);
  bf16* Vt = (bf16*)alloc(NTOK * DD * 2);
  float2* tbl = (float2*)alloc(NTOK * 32 * sizeof(float2));
  bf16* Oat = Xb;  // alias: Xb dead after fused QKV GEMM

  cvt_kernel<<<1024, 256, 0, stream>>>(X, Xb, (int)(NTOK * DD / 4));
  cvt4_kernel<<<1025, 256, 0, stream>>>(Wq, Wk, Wv, Wo, Wqb, Wkb, Wvb, Wob, mask, nm);
  sincos_table_kernel<<<1024, 256, 0, stream>>>(nm, tbl);

  gemm_qkv_kernel<<<(int)(NTOK / 128) * 24, 256, 0, stream>>>(Xb, Wqb, Wkb, Wvb, qls, kls, pds,
                                                              tbl, Qp, Kp, Vt);
  flash_kernel<<<1024, 256, 0, stream>>>(Qp, Kp, Vt, Oat, nm);
  gemm_bt_kernel<<<(int)(NTOK / 128) * (DD / 128), 256, 0, stream>>>(Oat, Wob, (float*)d_out,
                                                                     (int)NTOK, DD, DD);
}

// Round 17
// 188.065 us; speedup vs baseline: 1.1985x; 1.0233x over previous
//
#include <hip/hip_runtime.h>
#include <cstdint>
#include <cstddef>

#define BB 4
#define SS 2048
#define DD 1024
#define HH 16

typedef __bf16 bf16;
typedef __bf16 bf16x8 __attribute__((ext_vector_type(8)));
typedef __bf16 bf16x4 __attribute__((ext_vector_type(4)));
typedef float f32x4 __attribute__((ext_vector_type(4)));
typedef unsigned int u32;

typedef __attribute__((address_space(1))) const void* as1_cvoid;
typedef __attribute__((address_space(3))) void* as3_void;

__device__ __forceinline__ void gload_lds16(const void* g, void* l) {
  __builtin_amdgcn_global_load_lds((as1_cvoid)g, (as3_void)l, 16, 0, 0);
}

// ---------------- K1: merged prep: X cvt (blocks 0-1023), W cvt (1024-2047), mask (2048) ----------------
__global__ void prep_kernel(const float* __restrict__ X, bf16* __restrict__ Xb,
                            const float* __restrict__ W0, const float* __restrict__ W1,
                            const float* __restrict__ W2, const float* __restrict__ W3,
                            bf16* __restrict__ D0, bf16* __restrict__ D1,
                            bf16* __restrict__ D2, bf16* __restrict__ D3,
                            const unsigned char* __restrict__ mask, int* __restrict__ nm) {
  const int bid = blockIdx.x;
  if (bid < 1024) {  // X: 8M f32 -> bf16
    const int n4 = (int)(BB * SS * (size_t)DD / 4);
    for (int i = bid * 256 + threadIdx.x; i < n4; i += 262144) {
      float4 v = ((const float4*)X)[i];
      bf16x4 o;
      o[0] = (bf16)v.x; o[1] = (bf16)v.y; o[2] = (bf16)v.z; o[3] = (bf16)v.w;
      ((bf16x4*)Xb)[i] = o;
    }
    return;
  }
  if (bid == 2048) {  // per-batch mask count
    int wid = threadIdx.x >> 6, lane = threadIdx.x & 63;
    if (wid >= BB) return;
    int s = 0;
    for (int i = lane; i < SS; i += 64) s += (mask[wid * SS + i] != 0) ? 1 : 0;
#pragma unroll
    for (int m = 1; m < 64; m <<= 1) s += __shfl_xor(s, m);
    if (lane == 0) nm[wid] = s;
    return;
  }
  const int wb = bid - 1024;  // weights: 4 x 256 blocks
  int which = wb >> 8;
  const float* src = which == 0 ? W0 : which == 1 ? W1 : which == 2 ? W2 : W3;
  bf16* dst = which == 0 ? D0 : which == 1 ? D1 : which == 2 ? D2 : D3;
  const int n4 = DD * DD / 4;
  for (int i = (wb & 255) * 256 + threadIdx.x; i < n4; i += 65536) {
    float4 v = ((const float4*)src)[i];
    bf16x4 o;
    o[0] = (bf16)v.x; o[1] = (bf16)v.y; o[2] = (bf16)v.z; o[3] = (bf16)v.w;
    ((bf16x4*)dst)[i] = o;
  }
}

// ---------------- K1b: RoPE sin/cos table ----------------
__global__ void sincos_table_kernel(const int* __restrict__ nm, float2* __restrict__ tbl) {
  int g = blockIdx.x * 256 + threadIdx.x;  // (b*S+s)*32 + j
  int j = g & 31;
  int idx = g >> 5;
  int b = idx >> 11, s = idx & 2047;
  int pos = s - nm[b];
  float inv_ts = __expf((float)j * (-9.210340371976184f / 32.0f));
  float sn, cs;
  sincosf((float)pos * inv_ts, &sn, &cs);
  tbl[g] = make_float2(cs, sn);
}

// ---------------- K2: fused QKV GEMM + RoPE/RMS/scale epilogue (R12 proven) ----------------
__global__ void __launch_bounds__(256) gemm_qkv_kernel(
    const bf16* __restrict__ A, const bf16* __restrict__ Wq, const bf16* __restrict__ Wk,
    const bf16* __restrict__ Wv, const float* __restrict__ qls, const float* __restrict__ kls,
    const float* __restrict__ pds, const float2* __restrict__ tbl,
    bf16* __restrict__ Qp, bf16* __restrict__ Kp, bf16* __restrict__ Vt) {
  __shared__ __align__(16) char smem[4 * 64 * 72 * 2];
  bf16* Ab = (bf16*)smem;
  bf16* Bb = (bf16*)(smem + 8192);
  const int tid = threadIdx.x;
  const int wid = tid >> 6, lane = tid & 63;
  const int lr = lane & 15, lg = lane >> 4;
  const int K = DD;
  const int nx = 24;
  const int cpx = gridDim.x >> 3;
  const int lid = (blockIdx.x & 7) * cpx + (blockIdx.x >> 3);
  const int m0 = (lid / nx) * 128;
  const int ntile = lid % nx;
  const int which = ntile >> 3;
  const int n0 = (ntile & 7) * 128;
  const bf16* Bm = which == 0 ? Wq : (which == 1 ? Wk : Wv);
  const int wm = (wid >> 1) * 64, wn = (wid & 1) * 64;
  f32x4 acc[4][4] = {};
  for (int k0 = 0; k0 < K; k0 += 32) {
    __syncthreads();
#pragma unroll
    for (int i = 0; i < 2; ++i) {
      int o = (wid * 2 + i) * 1024 + lane * 16;
      int row = o >> 6;
      int ke = (o & 63) >> 1;
      gload_lds16(A + (size_t)(m0 + row) * K + k0 + ke, (char*)Ab + o);
      gload_lds16(Bm + (size_t)(n0 + row) * K + k0 + ke, (char*)Bb + o);
    }
    __syncthreads();
    bf16x8 af[4], bf_[4];
#pragma unroll
    for (int i = 0; i < 4; ++i) af[i] = *(const bf16x8*)&Ab[(wm + i * 16 + lr) * 32 + lg * 8];
#pragma unroll
    for (int j = 0; j < 4; ++j) bf_[j] = *(const bf16x8*)&Bb[(wn + j * 16 + lr) * 32 + lg * 8];
#pragma unroll
    for (int i = 0; i < 4; ++i)
#pragma unroll
      for (int j = 0; j < 4; ++j)
        acc[i][j] = __builtin_amdgcn_mfma_f32_16x16x32_bf16(af[i], bf_[j], acc[i][j], 0, 0, 0);
  }
  const int b = m0 >> 11;
  const int s0g = m0 & 2047;
  const int hq = n0 >> 6;
  if (which < 2) {
    float scj[4];
#pragma unroll
    for (int j = 0; j < 4; ++j) {
      int d = j * 16 + lr;
      scj[j] = (which == 0) ? qls[d] * 0.26017112262570096f * log1pf(__expf(pds[d]))
                            : kls[d];
    }
    bf16* Out = which == 0 ? Qp : Kp;
    const int h = hq + (wn >> 6);
    const size_t base = (size_t)(b * 16 + h) * SS;
#pragma unroll
    for (int i = 0; i < 4; ++i)
#pragma unroll
      for (int r = 0; r < 4; ++r) {
        int srow = s0g + wm + i * 16 + lg * 4 + r;
        const float2* trow = tbl + ((size_t)(b * SS + srow) << 5);
        float2 t0 = trow[lr], t1 = trow[16 + lr];
        float a0 = acc[i][0][r], a1 = acc[i][1][r], a2 = acc[i][2][r], a3 = acc[i][3][r];
        float n0_ = a0 * t0.x - a2 * t0.y;
        float n2_ = a2 * t0.x + a0 * t0.y;
        float n1_ = a1 * t1.x - a3 * t1.y;
        float n3_ = a3 * t1.x + a1 * t1.y;
        float ssum = n0_ * n0_ + n1_ * n1_ + n2_ * n2_ + n3_ * n3_;
        ssum += __shfl_xor(ssum, 1);
        ssum += __shfl_xor(ssum, 2);
        ssum += __shfl_xor(ssum, 4);
        ssum += __shfl_xor(ssum, 8);
        float rinv = rsqrtf(ssum * (1.0f / 64.0f) + 1e-6f);
        bf16* orow = Out + (base + srow) * 64;
        orow[lr]      = (bf16)(n0_ * rinv * scj[0]);
        orow[16 + lr] = (bf16)(n1_ * rinv * scj[1]);
        orow[32 + lr] = (bf16)(n2_ * rinv * scj[2]);
        orow[48 + lr] = (bf16)(n3_ * rinv * scj[3]);
      }
  } else {
    __syncthreads();
    bf16* tw = (bf16*)smem + wid * 64 * 72;
#pragma unroll
    for (int i = 0; i < 4; ++i)
#pragma unroll
      for (int j = 0; j < 4; ++j)
#pragma unroll
        for (int r = 0; r < 4; ++r)
          tw[(j * 16 + lr) * 72 + i * 16 + lg * 4 + r] = (bf16)acc[i][j][r];
    __syncthreads();
    int d = tid >> 2, sc = (tid & 3) * 16;
#pragma unroll
    for (int w = 0; w < 4; ++w) {
      int rh = w >> 1, hh = w & 1;
      const bf16* ts = (const bf16*)smem + w * 64 * 72 + d * 72 + sc;
      bf16x8 v0 = *(const bf16x8*)ts;
      bf16x8 v1 = *(const bf16x8*)(ts + 8);
      size_t vo = ((size_t)((b * 16 + hq + hh) * 64 + d)) * SS + s0g + rh * 64 + sc;
      *(bf16x8*)(Vt + vo) = v0;
      *(bf16x8*)(Vt + vo + 8) = v1;
    }
  }
}

// ---------------- K5: C[M,N] = A[M,K] @ B[N,K]^T (f32 out, for Wo) ----------------
__global__ void __launch_bounds__(256) gemm_bt_kernel(const bf16* __restrict__ A,
                                                      const bf16* __restrict__ Bm,
                                                      float* __restrict__ Cout,
                                                      int M, int N, int K) {
  __shared__ bf16 Ab[128 * 32];
  __shared__ bf16 Bb[128 * 32];
  const int tid = threadIdx.x;
  const int wid = tid >> 6, lane = tid & 63;
  const int lr = lane & 15, lg = lane >> 4;
  const int nx = N >> 7;
  const int cpx = gridDim.x >> 3;
  const int lid = (blockIdx.x & 7) * cpx + (blockIdx.x >> 3);
  const int m0 = (lid / nx) * 128, n0 = (lid % nx) * 128;
  const int wm = (wid >> 1) * 64, wn = (wid & 1) * 64;
  f32x4 acc[4][4] = {};
  for (int k0 = 0; k0 < K; k0 += 32) {
    __syncthreads();
#pragma unroll
    for (int i = 0; i < 2; ++i) {
      int o = (wid * 2 + i) * 1024 + lane * 16;
      int row = o >> 6;
      int ke = (o & 63) >> 1;
      gload_lds16(A + (size_t)(m0 + row) * K + k0 + ke, (char*)Ab + o);
      gload_lds16(Bm + (size_t)(n0 + row) * K + k0 + ke, (char*)Bb + o);
    }
    __syncthreads();
    bf16x8 af[4], bf_[4];
#pragma unroll
    for (int i = 0; i < 4; ++i) af[i] = *(const bf16x8*)&Ab[(wm + i * 16 + lr) * 32 + lg * 8];
#pragma unroll
    for (int j = 0; j < 4; ++j) bf_[j] = *(const bf16x8*)&Bb[(wn + j * 16 + lr) * 32 + lg * 8];
#pragma unroll
    for (int i = 0; i < 4; ++i)
#pragma unroll
      for (int j = 0; j < 4; ++j)
        acc[i][j] = __builtin_amdgcn_mfma_f32_16x16x32_bf16(af[i], bf_[j], acc[i][j], 0, 0, 0);
  }
#pragma unroll
  for (int i = 0; i < 4; ++i)
#pragma unroll
    for (int j = 0; j < 4; ++j)
#pragma unroll
      for (int r = 0; r < 4; ++r) {
        int row = m0 + wm + i * 16 + lg * 4 + r;
        int col = n0 + wn + j * 16 + lr;
        Cout[(size_t)row * N + col] = acc[i][j][r];
      }
}

// ---------------- K4: causal flash attention (R8 artifact, measured 83.3us) ----------------
// bh=bid&63, px=bid>>6 (deep blocks dispatch first = LPT). Wave-paired 64-row strips
// (xA=31-px deep, xB=px shallow); fused QK^T reads each K-fragment once for both
// strips; per-strip softmax (max3 tree, defer-max THR=8 exp2-domain); P via padded
// per-wave LDS [36]; mid-tile vmcnt(2) awaits V(t) while K(t+1) flies; shared PV.
__global__ void __launch_bounds__(256, 2) flash_kernel(
    const bf16* __restrict__ Qp, const bf16* __restrict__ Kp, const bf16* __restrict__ Vt,
    bf16* __restrict__ O, const int* __restrict__ nm) {
  __shared__ bf16 Kb[2][64 * 64];
  __shared__ bf16 Vb[64 * 64];
  __shared__ u32 Pl[4][16][36];
  const int bh = blockIdx.x & 63;
  const int px = blockIdx.x >> 6;  // 0..15
  const int xA = 31 - px, xB = px;
  const int b = bh >> 4, h = bh & 15;
  const int tid = threadIdx.x;
  const int wid = tid >> 6, lane = tid & 63;
  const int lr = lane & 15, lg = lane >> 4;
  const int nmb = nm[b];
  const int wqA = xA * 64 + wid * 16;
  const int wqB = xB * 64 + wid * 16;
  const int nt = xA + 1;

  bf16x8 qfA[2], qfB[2];
#pragma unroll
  for (int kh = 0; kh < 2; ++kh) {
    qfA[kh] = *(const bf16x8*)(Qp + ((size_t)bh * SS + wqA + lr) * 64 + kh * 32 + lg * 8);
    qfB[kh] = *(const bf16x8*)(Qp + ((size_t)bh * SS + wqB + lr) * 64 + kh * 32 + lg * 8);
  }

  float mA = -1e30f, lA = 0.f, mB = -1e30f, lB = 0.f;
  f32x4 oA[4] = {}, oB[4] = {};

  auto STAGE_K = [&](int bi, int t) {
    const int kv0 = t * 64;
#pragma unroll
    for (int i = 0; i < 2; ++i) {
      int o = i * 4096 + tid * 16;
      int row = o >> 7;
      int c16 = ((o >> 4) & 7) ^ (row & 7);
      gload_lds16(Kp + ((size_t)bh * SS + kv0 + row) * 64 + c16 * 8, (char*)Kb[bi] + o);
    }
  };
  auto STAGE_V = [&](int t) {
    const int kv0 = t * 64;
#pragma unroll
    for (int i = 0; i < 2; ++i) {
      int o = i * 4096 + tid * 16;
      int row = o >> 7;
      int c16 = ((o >> 4) & 7) ^ (row & 7);
      gload_lds16(Vt + ((size_t)bh * 64 + row) * SS + kv0 + c16 * 8, (char*)Vb + o);
    }
  };

  STAGE_K(0, 0);
  STAGE_V(0);
  __syncthreads();
  int buf = 0;
  for (int t = 0; t < nt; ++t) {
    const int kv0 = t * 64;
    if (t + 1 < nt) STAGE_K(buf ^ 1, t + 1);  // stays in flight across V-barrier
    const bool actB = (t <= xB);
    bf16x8 pbA[2], pbB[2];
    f32x4 sA[4], sB[4];

    // ---- fused QK^T: one pass over Kb serves both strips ----
    __builtin_amdgcn_s_setprio(1);
#pragma unroll
    for (int j = 0; j < 4; ++j) {
      int row = j * 16 + lr;
      const char* kbase = (const char*)Kb[buf] + row * 128;
      bf16x8 kf0 = *(const bf16x8*)(kbase + ((lg ^ (row & 7)) << 4));
      bf16x8 kf1 = *(const bf16x8*)(kbase + (((4 + lg) ^ (row & 7)) << 4));
      f32x4 z = {};
      z = __builtin_amdgcn_mfma_f32_16x16x32_bf16(kf0, qfA[0], z, 0, 0, 0);
      z = __builtin_amdgcn_mfma_f32_16x16x32_bf16(kf1, qfA[1], z, 0, 0, 0);
      sA[j] = z;
      if (actB) {
        f32x4 z2 = {};
        z2 = __builtin_amdgcn_mfma_f32_16x16x32_bf16(kf0, qfB[0], z2, 0, 0, 0);
        z2 = __builtin_amdgcn_mfma_f32_16x16x32_bf16(kf1, qfB[1], z2, 0, 0, 0);
        sB[j] = z2;
      }
    }
    __builtin_amdgcn_s_setprio(0);

    auto SOFTMAX = [&](f32x4* s, float& m_r, float& l_pp, f32x4* oacc, bf16x8* pb,
                       int xS, int wqS) {
      if (t == xS) {  // causal boundary tile
        int qr = wqS + lr;
#pragma unroll
        for (int j = 0; j < 4; ++j) {
          int kvb = kv0 + j * 16 + lg * 4;
#pragma unroll
          for (int r = 0; r < 4; ++r)
            if (kvb + r > qr) s[j][r] = -1e30f;
        }
      }
      if (kv0 < nmb) {  // prefix-padding mask
#pragma unroll
        for (int j = 0; j < 4; ++j) {
          int kvb = kv0 + j * 16 + lg * 4;
#pragma unroll
          for (int r = 0; r < 4; ++r)
            if (kvb + r < nmb) s[j][r] = -1e30f;
        }
      }
      // max3-friendly reduction (8 instrs for 16 values)
      float t0 = fmaxf(fmaxf(s[0][0], s[0][1]), s[0][2]);
      float t1 = fmaxf(fmaxf(s[0][3], s[1][0]), s[1][1]);
      float t2 = fmaxf(fmaxf(s[1][2], s[1][3]), s[2][0]);
      float t3 = fmaxf(fmaxf(s[2][1], s[2][2]), s[2][3]);
      float t4 = fmaxf(fmaxf(s[3][0], s[3][1]), s[3][2]);
      float t5 = fmaxf(fmaxf(t0, t1), s[3][3]);
      float pm = fmaxf(fmaxf(t2, t3), fmaxf(t4, t5));
      if (!__all(pm - m_r <= 8.f)) {  // defer-max (exp2 domain, THR=8)
        pm = fmaxf(pm, __shfl_xor(pm, 16));
        pm = fmaxf(pm, __shfl_xor(pm, 32));
        float mn = fmaxf(m_r, pm);
        float scl = exp2f(m_r - mn);
        m_r = mn;
        l_pp *= scl;
        f32x4 sv = {scl, scl, scl, scl};
#pragma unroll
        for (int jd = 0; jd < 4; ++jd) oacc[jd] *= sv;
      }
      const float mloc = m_r;
      float lp = l_pp;
#pragma unroll
      for (int j = 0; j < 4; ++j) {
        float p0 = exp2f(s[j][0] - mloc), p1 = exp2f(s[j][1] - mloc);
        float p2 = exp2f(s[j][2] - mloc), p3 = exp2f(s[j][3] - mloc);
        lp += (p0 + p1) + (p2 + p3);
        union { bf16 hx[4]; uint2 u2; } pk;
        pk.hx[0] = (bf16)p0; pk.hx[1] = (bf16)p1;
        pk.hx[2] = (bf16)p2; pk.hx[3] = (bf16)p3;
        *(uint2*)&Pl[wid][lr][j * 8 + lg * 2] = pk.u2;
      }
      l_pp = lp;
#pragma unroll
      for (int kh = 0; kh < 2; ++kh) pb[kh] = *(const bf16x8*)&Pl[wid][lr][kh * 16 + lg * 4];
    };

    SOFTMAX(sA, mA, lA, oA, pbA, xA, wqA);
    if (actB) SOFTMAX(sB, mB, lB, oB, pbB, xB, wqB);

    // ---- V[t] visibility (K[t+1] stays in flight) ----
    if (t > 0) {
      if (t + 1 < nt)
        asm volatile("s_waitcnt vmcnt(2)" ::: "memory");
      else
        asm volatile("s_waitcnt vmcnt(0)" ::: "memory");
      __builtin_amdgcn_s_barrier();
      __builtin_amdgcn_sched_barrier(0);
    }
    __builtin_amdgcn_s_setprio(1);
#pragma unroll
    for (int jd = 0; jd < 4; ++jd) {
      int row = jd * 16 + lr;
      const char* vbase = (const char*)Vb + row * 128;
      bf16x8 va0 = *(const bf16x8*)(vbase + ((lg ^ (row & 7)) << 4));
      bf16x8 va1 = *(const bf16x8*)(vbase + (((4 + lg) ^ (row & 7)) << 4));
      oA[jd] = __builtin_amdgcn_mfma_f32_16x16x32_bf16(va0, pbA[0], oA[jd], 0, 0, 0);
      oA[jd] = __builtin_amdgcn_mfma_f32_16x16x32_bf16(va1, pbA[1], oA[jd], 0, 0, 0);
      if (actB) {
        oB[jd] = __builtin_amdgcn_mfma_f32_16x16x32_bf16(va0, pbB[0], oB[jd], 0, 0, 0);
        oB[jd] = __builtin_amdgcn_mfma_f32_16x16x32_bf16(va1, pbB[1], oB[jd], 0, 0, 0);
      }
    }
    __builtin_amdgcn_s_setprio(0);
    __syncthreads();  // all waves done with Vb (and Kb[buf])
    if (t + 1 < nt) STAGE_V(t + 1);
    buf ^= 1;
  }
  // ---- epilogue ----
#pragma unroll
  for (int st = 0; st < 2; ++st) {
    float l = st == 0 ? lA : lB;
    const f32x4* oacc = st == 0 ? oA : oB;
    int wq = st == 0 ? wqA : wqB;
    l += __shfl_xor(l, 16);
    l += __shfl_xor(l, 32);
    float invl = 1.0f / l;
    size_t rowoff = ((size_t)b * SS + wq + lr) * DD + h * 64;
#pragma unroll
    for (int jd = 0; jd < 4; ++jd) {
      f32x4 ov = oacc[jd] * invl;
      bf16x4 hv;
      hv[0] = (bf16)ov[0]; hv[1] = (bf16)ov[1]; hv[2] = (bf16)ov[2]; hv[3] = (bf16)ov[3];
      *(bf16x4*)(O + rowoff + jd * 16 + lg * 4) = hv;
    }
  }
}

// ---------------- host launch ----------------
extern "C" void kernel_launch(void* const* d_in, const int* in_sizes, int n_in,
                              void* d_out, int out_size, void* d_ws, size_t ws_size,
                              hipStream_t stream) {
  const float* X = (const float*)d_in[0];
  const float* Wq = (const float*)d_in[1];
  const float* Wk = (const float*)d_in[2];
  const float* Wv = (const float*)d_in[3];
  const float* Wo = (const float*)d_in[4];
  const float* qls = (const float*)d_in[5];
  const float* kls = (const float*)d_in[6];
  const float* pds = (const float*)d_in[7];
  const unsigned char* mask = (const unsigned char*)d_in[8];

  char* ws = (char*)d_ws;
  size_t off = 0;
  auto alloc = [&](size_t bytes) {
    char* p = ws + off;
    off += (bytes + 255) & ~(size_t)255;
    return p;
  };
  const size_t NTOK = (size_t)BB * SS;  // 8192
  int* nm = (int*)alloc(16);
  bf16* Xb = (bf16*)alloc(NTOK * DD * 2);
  bf16* Wqb = (bf16*)alloc((size_t)DD * DD * 2);
  bf16* Wkb = (bf16*)alloc((size_t)DD * DD * 2);
  bf16* Wvb = (bf16*)alloc((size_t)DD * DD * 2);
  bf16* Wob = (bf16*)alloc((size_t)DD * DD * 2);
  bf16* Qp = (bf16*)alloc(NTOK * DD * 2);
  bf16* Kp = (bf16*)alloc(NTOK * DD * 2);
  bf16* Vt = (bf16*)alloc(NTOK * DD * 2);
  float2* tbl = (float2*)alloc(NTOK * 32 * sizeof(float2));
  bf16* Oat = Xb;  // alias: Xb dead after fused QKV GEMM

  prep_kernel<<<2049, 256, 0, stream>>>(X, Xb, Wq, Wk, Wv, Wo, Wqb, Wkb, Wvb, Wob, mask, nm);
  sincos_table_kernel<<<1024, 256, 0, stream>>>(nm, tbl);

  gemm_qkv_kernel<<<(int)(NTOK / 128) * 24, 256, 0, stream>>>(Xb, Wqb, Wkb, Wvb, qls, kls, pds,
                                                              tbl, Qp, Kp, Vt);
  flash_kernel<<<1024, 256, 0, stream>>>(Qp, Kp, Vt, Oat, nm);
  gemm_bt_kernel<<<(int)(NTOK / 128) * (DD / 128), 256, 0, stream>>>(Oat, Wob, (float*)d_out,
                                                                     (int)NTOK, DD, DD);
}